// Round 1
// baseline (1524.196 us; speedup 1.0000x reference)
//
#include <hip/hip_runtime.h>
#include <stdint.h>

typedef unsigned int u32;
typedef unsigned short u16;

#define NB 16
#define NL 4097      // x0 rows per batch (= att2 keys - 1)
#define NM_ROWS 1025 // x1 rows per batch
#define DS 256
#define DM 512
#define DL 1024
#define NK1 1025     // att1 keys
#define NK2 4098     // att2 keys
#define MPROJ 4098   // proj_w output dim
#define NBLK 512     // persistent grid; 32KB LDS -> 5 blocks/CU capacity (1280 >> 512)

__device__ __forceinline__ float bf2f(u16 h){ union{u32 u; float f;} c; c.u = ((u32)h)<<16; return c.f; }
__device__ __forceinline__ u16 f2bf(float x){ union{float f; u32 u;} c; c.f=x; u32 u=c.u; return (u16)((u + 0x7fffu + ((u>>16)&1u))>>16); }
__device__ __forceinline__ float getel(const void* p, long i, int f){
  return f ? ((const float*)p)[i] : bf2f(((const u16*)p)[i]);
}
__device__ __forceinline__ void unpack8(uint4 v, float* fo){
  u32 wd[4]={v.x,v.y,v.z,v.w};
  #pragma unroll
  for(int i=0;i<4;i++){
    union{u32 u; float x;} a,b;
    a.u = wd[i]<<16; b.u = wd[i]&0xffff0000u;
    fo[2*i]=a.x; fo[2*i+1]=b.x;
  }
}
__device__ __forceinline__ float wsum(float v){
  #pragma unroll
  for(int o=32;o>0;o>>=1) v += __shfl_xor(v,o,64);
  return v;
}
__device__ __forceinline__ float wmaxr(float v){
  #pragma unroll
  for(int o=32;o>0;o>>=1) v = fmaxf(v, __shfl_xor(v,o,64));
  return v;
}
__device__ __forceinline__ float block_sum(float v, volatile float* red){
  v = wsum(v);
  if((threadIdx.x&63)==0) red[threadIdx.x>>6]=v;
  __syncthreads();
  float r = red[0]+red[1]+red[2]+red[3];
  __syncthreads();
  return r;
}
__device__ __forceinline__ float block_max(float v, volatile float* red){
  v = wmaxr(v);
  if((threadIdx.x&63)==0) red[threadIdx.x>>6]=v;
  __syncthreads();
  float r = fmaxf(fmaxf(red[0],red[1]),fmaxf(red[2],red[3]));
  __syncthreads();
  return r;
}
__device__ __forceinline__ float clamp60(float x){ return fminf(fmaxf(x,-60.f),60.f); }

// ---- grid barrier: fresh zeroed counter per phase (host memset), release/acquire
// at agent scope per Guideline 16 (cross-XCD L2 non-coherence). All blocks are
// guaranteed co-resident: 512 blocks, 32KB LDS => 5/CU capacity; launch_bounds(256,2)
// caps VGPR at 256 => >=2 blocks/CU. ----
__device__ __forceinline__ void gsync(int* bar, int i){
  __syncthreads();
  __threadfence();                      // release: publish this block's writes
  if (threadIdx.x == 0){
    __hip_atomic_fetch_add(&bar[i], 1, __ATOMIC_ACQ_REL, __HIP_MEMORY_SCOPE_AGENT);
    while (__hip_atomic_load(&bar[i], __ATOMIC_RELAXED, __HIP_MEMORY_SCOPE_AGENT) < NBLK)
      __builtin_amdgcn_s_sleep(2);
  }
  __syncthreads();
  __threadfence();                      // acquire: invalidate L1 so all lanes see fresh data
}

// ---- batched matvec phase: out[b,m] = bias[m] + sum_d W[m,d]*x[b,d]
// blocks [b0, b0+nb) participate; wave -> one m. ----
struct GJob {
  const void* W; const void* x; const void* bias; float* out;
  int M; int D; long xstride; int xinws; int b0; int nb;
};

__device__ void gemv_phase(const GJob j, int f, float* xs){
  int rel = (int)blockIdx.x - j.b0;
  if (rel < 0 || rel >= j.nb) return;
  int tid = threadIdx.x;
  int w = tid>>6, l = tid&63;
  int m = rel*4 + w;
  float acc[NB];
  #pragma unroll
  for(int b=0;b<NB;b++) acc[b]=0.f;
  for (int c0=0; c0<j.D; c0+=512){
    int cl = j.D-c0; if (cl>512) cl=512;
    for (int i=tid;i<NB*cl;i+=256){
      int b=i/cl, d=i-b*cl;
      float v;
      if (j.xinws) v = ((const float*)j.x)[(long)b*j.D + c0 + d];
      else         v = getel(j.x, (long)b*j.xstride + c0 + d, f);
      xs[i]=v;
    }
    __syncthreads();
    if (m < j.M){
      for (int d=l; d<cl; d+=64){
        float wv = getel(j.W, (long)m*j.D + c0 + d, f);
        #pragma unroll
        for(int b=0;b<NB;b++) acc[b] += wv*xs[b*cl+d];
      }
    }
    __syncthreads();
  }
  if (m >= j.M) return;
  #pragma unroll
  for(int b=0;b<NB;b++) acc[b]=wsum(acc[b]);
  if (l==0){
    float bv = j.bias ? getel(j.bias, m, f) : 0.f;
    #pragma unroll
    for(int b=0;b<NB;b++) j.out[(long)b*j.M+m]=acc[b]+bv;
  }
}

// ---- transpose matvec phase: out[b,d] += sum_m W[m,d]*x[b,m] (out pre-zeroed) ----
__device__ void tgemv_phase(const void* W, const float* x, float* out, int M, int D,
                            int b0, int lgDch, int f, float* xs){
  int nDch = D>>8, nMch = M>>6;
  int rel = (int)blockIdx.x - b0;
  if (rel < 0 || rel >= nDch*nMch) return;
  int tid = threadIdx.x;
  int bx = rel & (nDch-1);
  int by = rel >> lgDch;
  int m0 = by*64;
  int d = bx*256 + tid;
  for (int i=tid;i<NB*64;i+=256){ int b=i>>6, mm=i&63; xs[i]=x[(long)b*M + m0+mm]; }
  __syncthreads();
  float acc[NB];
  #pragma unroll
  for(int b=0;b<NB;b++) acc[b]=0.f;
  for (int mm=0;mm<64;++mm){
    float wv = getel(W, (long)(m0+mm)*D + d, f);
    #pragma unroll
    for(int b=0;b<NB;b++) acc[b] += wv*xs[b*64+mm];
  }
  #pragma unroll
  for(int b=0;b<NB;b++) atomicAdd(&out[(long)b*D+d], acc[b]);
}

__global__ __launch_bounds__(256, 2) void mega_kernel(
    const void* __restrict__ x0, const void* __restrict__ x1, const void* __restrict__ x2,
    const void* __restrict__ f_s_w, const void* __restrict__ f_s_b,
    const void* __restrict__ f_m_w, const void* __restrict__ f_m_b,
    const void* __restrict__ Wq1, const void* __restrict__ Wk1,
    const void* __restrict__ Wq2, const void* __restrict__ Wk2, const void* __restrict__ Wv,
    const void* __restrict__ proj_w, const void* __restrict__ proj_b,
    const void* __restrict__ gs_w, const void* __restrict__ gs_b,
    float* __restrict__ ws, void* __restrict__ out)
{
  // ws layout (must match host)
  float* cls_s_proj = ws;                      // 16*512
  float* cls_m_proj = cls_s_proj + NB*DM;      // 16*1024
  float* q1v        = cls_m_proj + NB*DL;      // 16*512
  float* q2v        = q1v + NB*DM;             // 16*1024
  float* logits1    = q2v + NB*DL;             // 16*1025 (index 0 unused)
  float* att1_sm    = logits1 + NB*NK1;        // 16*1025
  float* att1w      = att1_sm + NB*NK1;        // 16*4098 (pre-scaled by 0.3)
  float* uvec       = att1w + NB*NK2;          // 16*1024
  float* outv       = uvec + NB*DL;            // 16*1024
  float* g_s        = outv + NB*DL;            // 16*256
  float* q1p        = g_s + NB*DS;             // 16*512   <- zeroed
  float* q2p        = q1p + NB*DM;             // 16*1024  <- zeroed
  float* s1         = q2p + NB*DL;             // 16*1024  <- zeroed
  float* s2         = s1 + NB*DL;              // 16*1024  <- zeroed
  float* Zacc       = s2 + NB*DL;              // 16       <- zeroed
  int*   bar        = (int*)(Zacc + NB);       // 16 ints  <- zeroed (barrier counters)

  __shared__ float smem[8192];                 // 32 KB, reused per phase

  const int blk = (int)blockIdx.x;
  const int tid = (int)threadIdx.x;
  const int w = tid>>6, l = tid&63;

  // ---- Ph0: per-block dtype detect (block-local, no barrier needed) ----
  int f;
  {
    float mx=0.f;
    const u16* p = (const u16*)x0;
    for (int i=tid;i<4096;i+=256){ float v=fabsf(bf2f(p[i])); if(v==v) mx=fmaxf(mx,v); }
    smem[tid]=mx; __syncthreads();
    if (tid==0){
      float m=0.f;
      for (int i=0;i<256;i++) m=fmaxf(m,smem[i]);
      smem[0] = (m>1e3f)?1.f:0.f;
    }
    __syncthreads();
    f = (smem[0]!=0.f)?1:0;
    __syncthreads();
  }

  // ---- Ph1: cls projections ----
  gemv_phase(GJob{f_s_w, x2, f_s_b, cls_s_proj, DM, DS, (long)NL*DS, 0, 0, 128}, f, smem);
  gemv_phase(GJob{f_m_w, x1, f_m_b, cls_m_proj, DL, DM, (long)NM_ROWS*DM, 0, 128, 256}, f, smem);
  gsync(bar, 0);

  // ---- Ph2: q1 = Wq1@csp, q2 = Wq2@cmp ----
  gemv_phase(GJob{Wq1, cls_s_proj, nullptr, q1v, DM, DM, 0, 1, 0, 128}, f, smem);
  gemv_phase(GJob{Wq2, cls_m_proj, nullptr, q2v, DL, DL, 0, 1, 128, 256}, f, smem);
  gsync(bar, 1);

  // ---- Ph3: q1p = Wk1^T@q1, q2p = Wk2^T@q2 (atomics into zeroed bufs) ----
  tgemv_phase(Wk1, q1v, q1p, DM, DM, 0, 1, f, smem);
  tgemv_phase(Wk2, q2v, q2p, DL, DL, 16, 2, f, smem);
  gsync(bar, 2);

  // ---- Ph4: att1 logits for keys 1..1024 (8 keys per wave) ----
  {
    int Wd = blk*4 + w;                 // wave id in [0,2048)
    int b = Wd>>7, widx = Wd&127;
    const float* qp = q1p + (long)b*DM + (long)l*8;
    float qv[8];
    #pragma unroll
    for (int j2=0;j2<8;j2++) qv[j2]=qp[j2];
    for (int t=0;t<8;t++){
      int k = widx*8 + t + 1;           // 1..1024
      long rbase = ((long)b*NM_ROWS + k)*DM + (long)l*8;
      float rf[8];
      if (f){
        const float* rp = (const float*)x1 + rbase;
        float4 a0 = *(const float4*)rp;
        float4 a1 = *(const float4*)(rp+4);
        rf[0]=a0.x; rf[1]=a0.y; rf[2]=a0.z; rf[3]=a0.w;
        rf[4]=a1.x; rf[5]=a1.y; rf[6]=a1.z; rf[7]=a1.w;
      } else {
        uint4 rv = *(const uint4*)((const u16*)x1 + rbase);
        unpack8(rv, rf);
      }
      float s = rf[0]*qv[0]+rf[1]*qv[1]+rf[2]*qv[2]+rf[3]*qv[3]
              + rf[4]*qv[4]+rf[5]*qv[5]+rf[6]*qv[6]+rf[7]*qv[7];
      s = wsum(s);
      if (l==0) logits1[(long)b*NK1+k] = s*(1.f/22.f);
    }
  }
  gsync(bar, 3);

  // ---- Ph5: att1 softmax (blocks 0..15) ----
  if (blk < NB){
    int b = blk;
    volatile float* red = smem;
    float p=0.f;
    for (int d2=tid; d2<DM; d2+=256) p += q1p[(long)b*DM+d2]*cls_s_proj[(long)b*DM+d2];
    float l0 = block_sum(p, red) * (1.f/22.f);
    float mx = l0;
    for (int k=1+tid;k<NK1;k+=256) mx = fmaxf(mx, logits1[(long)b*NK1+k]);
    mx = block_max(mx, red);
    float s=0.f;
    for (int k=tid;k<NK1;k+=256){
      float lg = (k==0)? l0 : logits1[(long)b*NK1+k];
      float e = __expf(clamp60(lg-mx));
      att1_sm[(long)b*NK1+k]=e;
      s+=e;
    }
    s = block_sum(s, red);
    float inv = 1.f/fmaxf(s,1e-30f);
    for (int k=tid;k<NK1;k+=256) att1_sm[(long)b*NK1+k]*=inv;
  }
  gsync(bar, 4);

  // ---- Ph6: att1 projection: att1w[b,m] = 0.3*(proj_b[m] + sum_k sm[b,k]*proj_w[m,k]) ----
  {
    int base = blk*4 + w;                          // wave m-base in [0,2048)
    int trips = (MPROJ - blk*4 + 2047) / 2048;     // block-uniform
    for (int t=0;t<trips;t++){
      int m = base + t*2048;
      float acc[NB];
      #pragma unroll
      for (int b2=0;b2<NB;b2++) acc[b2]=0.f;
      for (int h=0;h<2;h++){
        for (int i=tid;i<8192;i+=256){ int bb=i>>10, k=i&1023; smem[i]=att1_sm[(long)(h*8+bb)*NK1+k]; }
        __syncthreads();
        if (m < MPROJ){
          for (int k=l;k<1024;k+=64){
            float wv = getel(proj_w, (long)m*NK1+k, f);
            #pragma unroll
            for (int bb=0;bb<8;bb++) acc[h*8+bb] += wv*smem[bb*1024+k];
          }
        }
        __syncthreads();
      }
      if (m < MPROJ){
        if (l==0){
          float wt = getel(proj_w, (long)m*NK1+1024, f);
          #pragma unroll
          for (int b2=0;b2<NB;b2++) acc[b2] += wt*att1_sm[(long)b2*NK1+1024];
        }
        #pragma unroll
        for (int b2=0;b2<NB;b2++) acc[b2]=wsum(acc[b2]);
        if (l==0){
          float pb = getel(proj_b, m, f);
          #pragma unroll
          for (int b2=0;b2<NB;b2++) att1w[(long)b2*NK2+m] = 0.3f*(acc[b2]+pb);
        }
      }
    }
  }
  gsync(bar, 5);

  // ---- Ph7: main pass over x0 (read once). 128 waves/batch, 33 keys/wave. ----
  {
    float* ls = smem;          // [4][1024]
    float* zs = smem + 4096;   // [4]
    int b = blk>>5;                          // 32 blocks per batch
    int widx = ((blk&31)<<2) + w;            // wave index within batch, [0,128)
    int kbase = widx*33;
    int nk = NL - kbase; if (nk>33) nk=33; if (nk<0) nk=0;
    float qf[16];
    {
      const float* qp = q2p + (long)b*DL;
      #pragma unroll
      for (int j2=0;j2<8;j2++){ qf[j2]=qp[l*8+j2]; qf[8+j2]=qp[512+l*8+j2]; }
    }
    float af1[16], af2[16];
    #pragma unroll
    for (int j2=0;j2<16;j2++){ af1[j2]=0.f; af2[j2]=0.f; }
    float zacc=0.f;
    const float* awp = att1w + (long)b*NK2 + kbase + 1;
    for (int i=0;i<nk;i++){
      float rf[16];
      long rowoff = ((long)b*NL + kbase + i)*DL;
      if (f){
        const float* rp = ((const float*)x0) + rowoff;
        float4 a0 = *(const float4*)(rp + l*8);
        float4 a1 = *(const float4*)(rp + l*8 + 4);
        float4 a2 = *(const float4*)(rp + 512 + l*8);
        float4 a3 = *(const float4*)(rp + 512 + l*8 + 4);
        rf[0]=a0.x; rf[1]=a0.y; rf[2]=a0.z; rf[3]=a0.w;
        rf[4]=a1.x; rf[5]=a1.y; rf[6]=a1.z; rf[7]=a1.w;
        rf[8]=a2.x; rf[9]=a2.y; rf[10]=a2.z; rf[11]=a2.w;
        rf[12]=a3.x; rf[13]=a3.y; rf[14]=a3.z; rf[15]=a3.w;
      } else {
        const u16* rp = ((const u16*)x0) + rowoff;
        uint4 rv0 = *(const uint4*)(rp + l*8);
        uint4 rv1 = *(const uint4*)(rp + 512 + l*8);
        u32 wd[8]={rv0.x,rv0.y,rv0.z,rv0.w,rv1.x,rv1.y,rv1.z,rv1.w};
        #pragma unroll
        for(int q=0;q<8;q++){
          union{u32 u; float x;} ua,ub;
          ua.u = wd[q]<<16; ub.u = wd[q]&0xffff0000u;
          rf[2*q]=ua.x; rf[2*q+1]=ub.x;
        }
      }
      float dp=0.f;
      #pragma unroll
      for (int j2=0;j2<16;j2++) dp += rf[j2]*qf[j2];
      dp = clamp60(wsum(dp)*(1.f/32.f));
      float e = __expf(dp);
      float aw = awp[i];
      zacc += e;
      #pragma unroll
      for (int j2=0;j2<16;j2++){ af1[j2] += aw*rf[j2]; af2[j2] += e*rf[j2]; }
    }
    #pragma unroll
    for (int c=0;c<2;c++)
      #pragma unroll
      for (int j2=0;j2<8;j2++) ls[w*1024 + c*512 + l*8 + j2] = af1[c*8+j2];
    __syncthreads();
    for (int d2=tid; d2<1024; d2+=256)
      atomicAdd(&s1[(long)b*DL+d2], ls[d2]+ls[1024+d2]+ls[2048+d2]+ls[3072+d2]);
    __syncthreads();
    #pragma unroll
    for (int c=0;c<2;c++)
      #pragma unroll
      for (int j2=0;j2<8;j2++) ls[w*1024 + c*512 + l*8 + j2] = af2[c*8+j2];
    if (l==0) zs[w]=zacc;
    __syncthreads();
    for (int d2=tid; d2<1024; d2+=256)
      atomicAdd(&s2[(long)b*DL+d2], ls[d2]+ls[1024+d2]+ls[2048+d2]+ls[3072+d2]);
    if (tid==0) atomicAdd(&Zacc[b], zs[0]+zs[1]+zs[2]+zs[3]);
  }
  gsync(bar, 6);

  // ---- Ph8: finalize u (blocks 0..15) ----
  if (blk < NB){
    int b = blk;
    volatile float* red = smem;
    float p=0.f;
    for (int d2=tid;d2<DL;d2+=256) p += q2p[(long)b*DL+d2]*cls_m_proj[(long)b*DL+d2];
    float l20 = clamp60(block_sum(p,red)*(1.f/32.f));
    float e0 = __expf(l20);
    float Zf = fmaxf(Zacc[b] + e0, 1e-30f);
    float a0 = att1w[(long)b*NK2];
    float c7 = 0.7f/Zf;
    for (int d2=tid;d2<DL;d2+=256){
      float cm = cls_m_proj[(long)b*DL+d2];
      uvec[(long)b*DL+d2] = s1[(long)b*DL+d2] + a0*cm + c7*(s2[(long)b*DL+d2] + e0*cm);
    }
  }
  gsync(bar, 7);

  // ---- Ph9: outv = Wv@u ----
  gemv_phase(GJob{Wv, uvec, nullptr, outv, DL, DL, 0, 1, 0, 256}, f, smem);
  gsync(bar, 8);

  // ---- Ph10: g_s = gs_w@outv + gs_b ----
  gemv_phase(GJob{gs_w, outv, gs_b, g_s, DS, DL, 0, 1, 0, 64}, f, smem);
  gsync(bar, 9);

  // ---- Ph11: broadcast g_s[b] to all 4097 output rows ----
  {
    int colq = tid & 31;   // 32 chunks of 8 elems per 256-elem row
    int rowo = tid >> 5;   // 8 rows per block per step
    const long total = (long)NB*NL;
    for (long idx = (long)blk*8 + rowo; idx < total; idx += (long)NBLK*8){
      int b = (int)(idx / NL);
      const float* gp = g_s + (long)b*DS + colq*8;
      float4 ga = *(const float4*)gp;
      float4 gb = *(const float4*)(gp+4);
      if (f){
        float4* op = (float4*)out + idx*64 + colq*2;
        op[0]=ga; op[1]=gb;
      } else {
        uint4 pk;
        pk.x = (u32)f2bf(ga.x) | ((u32)f2bf(ga.y)<<16);
        pk.y = (u32)f2bf(ga.z) | ((u32)f2bf(ga.w)<<16);
        pk.z = (u32)f2bf(gb.x) | ((u32)f2bf(gb.y)<<16);
        pk.w = (u32)f2bf(gb.z) | ((u32)f2bf(gb.w)<<16);
        ((uint4*)out)[idx*32 + colq] = pk;
      }
    }
  }
}

extern "C" void kernel_launch(void* const* d_in, const int* in_sizes, int n_in,
                              void* d_out, int out_size, void* d_ws, size_t ws_size,
                              hipStream_t stream) {
  const void* x0     = d_in[0];
  const void* x1     = d_in[1];
  const void* x2     = d_in[2];
  const void* f_s_w  = d_in[3];
  const void* f_s_b  = d_in[4];
  const void* f_m_w  = d_in[5];
  const void* f_m_b  = d_in[6];
  const void* Wq1    = d_in[7];
  const void* Wk1    = d_in[8];
  const void* Wq2    = d_in[9];
  const void* Wk2    = d_in[10];
  const void* Wv     = d_in[11];
  const void* proj_w = d_in[12];
  const void* proj_b = d_in[13];
  const void* gs_w   = d_in[14];
  const void* gs_b   = d_in[15];

  float* ws = (float*)d_ws;
  // zero region: q1p, q2p, s1, s2, Zacc, bar[16]
  float* q1p = ws + (size_t)NB*(DM + DL + DM + DL + NK1 + NK1 + NK2 + DL + DL + DS);
  size_t zero_bytes = (size_t)(NB*DM + 3*NB*DL + NB)*sizeof(float) + 16*sizeof(int);
  hipMemsetAsync(q1p, 0, zero_bytes, stream);

  mega_kernel<<<dim3(NBLK), dim3(256), 0, stream>>>(
      x0, x1, x2, f_s_w, f_s_b, f_m_w, f_m_b,
      Wq1, Wk1, Wq2, Wk2, Wv, proj_w, proj_b, gs_w, gs_b,
      ws, d_out);
}

// Round 2
// 960.147 us; speedup vs baseline: 1.5875x; 1.5875x over previous
//
#include <hip/hip_runtime.h>
#include <stdint.h>

typedef unsigned int u32;
typedef unsigned short u16;

#define NB 16
#define NL 4097      // x0 rows per batch (= att2 keys - 1)
#define NM_ROWS 1025 // x1 rows per batch
#define DS 256
#define DM 512
#define DL 1024
#define NK1 1025     // att1 keys
#define NK2 4098     // att2 keys
#define MPROJ 4098   // proj_w output dim

// ---- workspace layout (float offsets) ----
#define OFF_CSP  0            // 16*512
#define OFF_CMP  8192         // 16*1024
#define OFF_Q1V  24576        // 16*512
#define OFF_Q2V  32768        // 16*1024
#define OFF_E1   49152        // 16*1025  unnormalized exp(att1 logits)
#define OFF_A1W  65552        // 16*4098  0.3*normalized proj output
#define OFF_GS   131120       // 16*256
#define OFF_WF   135216       // 256*1024 Wfuse = gs_w @ Wv
#define OFF_Q1P  397360       // 16*512   <- zeroed
#define OFF_Q2P  405552       // 16*1024  <- zeroed
#define OFF_S1   421936       // 16*1024  <- zeroed
#define OFF_S2   438320       // 16*1024  <- zeroed
#define OFF_ZA   454704       // 16       <- zeroed (att2 Z)
#define OFF_Z1   454720       // 16       <- zeroed (att1 Z)
#define OFF_E20  454736       // 16       <- zeroed (att2 cls-key exp)
#define OFF_FLAG 454752       // 1 int (written by init every iter, not zeroed)
#define ZERO_U4  14348        // (454752-397360)/4 uint4s to zero

__device__ __forceinline__ float bf2f(u16 h){ union{u32 u; float f;} c; c.u = ((u32)h)<<16; return c.f; }
__device__ __forceinline__ u16 f2bf(float x){ union{float f; u32 u;} c; c.f=x; u32 u=c.u; return (u16)((u + 0x7fffu + ((u>>16)&1u))>>16); }
__device__ __forceinline__ float getel(const void* p, long i, int f){
  return f ? ((const float*)p)[i] : bf2f(((const u16*)p)[i]);
}
__device__ __forceinline__ void unpack8(uint4 v, float* fo){
  u32 wd[4]={v.x,v.y,v.z,v.w};
  #pragma unroll
  for(int i=0;i<4;i++){
    union{u32 u; float x;} a,b;
    a.u = wd[i]<<16; b.u = wd[i]&0xffff0000u;
    fo[2*i]=a.x; fo[2*i+1]=b.x;
  }
}
__device__ __forceinline__ float wsum(float v){
  #pragma unroll
  for(int o=32;o>0;o>>=1) v += __shfl_xor(v,o,64);
  return v;
}
__device__ __forceinline__ float block_sum(float v, volatile float* red){
  v = wsum(v);
  if((threadIdx.x&63)==0) red[threadIdx.x>>6]=v;
  __syncthreads();
  float r = red[0]+red[1]+red[2]+red[3];
  __syncthreads();
  return r;
}
__device__ __forceinline__ float clamp60(float x){ return fminf(fmaxf(x,-60.f),60.f); }

__device__ __forceinline__ int self_detect(const void* x0, float* sh){
  // per-block dtype detect: read 4096 u16 of x0; bf16 data has max|v| ~5,
  // fp32 bits read as u16 halves decode to huge bf16 values w.h.p.
  float mx=0.f;
  const u16* p = (const u16*)x0;
  for (int i=threadIdx.x;i<4096;i+=256){ float v=fabsf(bf2f(p[i])); if(v==v) mx=fmaxf(mx,v); }
  sh[threadIdx.x]=mx; __syncthreads();
  if (threadIdx.x==0){
    float m=0.f;
    for (int i=0;i<256;i++) m=fmaxf(m,sh[i]);
    sh[0] = (m>1e3f)?1.f:0.f;
  }
  __syncthreads();
  int f = (sh[0]!=0.f)?1:0;
  __syncthreads();
  return f;
}

// ---- init: blocks 0..63 Wfuse tiles; 64..95 zero accumulators; 96 detect+flag ----
__global__ __launch_bounds__(256) void init_kernel(const void* __restrict__ x0,
    const void* __restrict__ gs_w, const void* __restrict__ Wv,
    float* __restrict__ ws, int* __restrict__ flag){
  __shared__ float sh[1280];
  int blk = blockIdx.x, tid = threadIdx.x;
  if (blk >= 64 && blk < 96){
    uint4 z; z.x=0u; z.y=0u; z.z=0u; z.w=0u;
    uint4* zp = (uint4*)(ws + OFF_Q1P);
    for (int i=(blk-64)*256+tid; i<ZERO_U4; i+=32*256) zp[i]=z;
    return;
  }
  if (blk == 96){
    int f = self_detect(x0, sh);
    if (tid==0) flag[0]=f;
    return;
  }
  // Wfuse[o,d] = sum_m gs_w[o,m]*Wv[m,d]; block -> 16 o-rows x 256 d-cols
  int f = self_detect(x0, sh);
  int o0 = (blk>>2)*16;
  int d  = (blk&3)*256 + tid;
  float acc[16];
  #pragma unroll
  for(int o=0;o<16;o++) acc[o]=0.f;
  for (int m0=0;m0<DL;m0+=64){
    for (int i=tid;i<1024;i+=256){ int oo=i>>6, mm=i&63; sh[i]=getel(gs_w,(long)(o0+oo)*DL+m0+mm,f); }
    __syncthreads();
    for (int mm=0;mm<64;++mm){
      float wv = getel(Wv,(long)(m0+mm)*DL+d,f);
      #pragma unroll
      for(int o=0;o<16;o++) acc[o] += sh[o*64+mm]*wv;
    }
    __syncthreads();
  }
  float* WF = ws + OFF_WF;
  #pragma unroll
  for(int o=0;o<16;o++) WF[(long)(o0+o)*DL+d]=acc[o];
}

// ---- batched matvec: out[b,m] = bias[m] + sum_d W[m,d]*x[b,d] ----
struct Job {
  const void* W; const void* x; const void* bias; float* out;
  int M, D; long xstride; int xinws;
};

__global__ __launch_bounds__(256) void gemv_n_kernel(Job j0, Job j1, const int* __restrict__ flagp){
  Job j = (blockIdx.y==0)? j0 : j1;
  if ((int)(blockIdx.x*4) >= j.M) return;
  int f = flagp[0];
  __shared__ float xs[NB*512];
  int tid = threadIdx.x;
  int m = blockIdx.x*4 + (tid>>6);
  int l = tid & 63;
  float acc[NB];
  #pragma unroll
  for(int b=0;b<NB;b++) acc[b]=0.f;
  for(int c0=0;c0<j.D;c0+=512){
    int cl = j.D-c0; if (cl>512) cl=512;
    for(int i=tid;i<NB*cl;i+=256){
      int b=i/cl, d=i-b*cl;
      float v;
      if (j.xinws) v = ((const float*)j.x)[(long)b*j.D + c0 + d];
      else         v = getel(j.x, (long)b*j.xstride + c0 + d, f);
      xs[i]=v;
    }
    __syncthreads();
    if (m < j.M){
      for(int d=l; d<cl; d+=64){
        float w = getel(j.W, (long)m*j.D + c0 + d, f);
        #pragma unroll
        for(int b=0;b<NB;b++) acc[b] += w*xs[b*cl+d];
      }
    }
    __syncthreads();
  }
  if (m >= j.M) return;
  #pragma unroll
  for(int b=0;b<NB;b++) acc[b]=wsum(acc[b]);
  if(l==0){
    float bv = j.bias ? getel(j.bias, m, f) : 0.f;
    #pragma unroll
    for(int b=0;b<NB;b++) j.out[(long)b*j.M+m]=acc[b]+bv;
  }
}

// ---- transpose matvec: out[b,d] += sum_m W[m,d]*x[b,m] (out pre-zeroed) ----
struct TJob { const void* W; const float* x; float* out; int M, D; };

__global__ __launch_bounds__(256) void gemv_t_kernel(TJob j0, TJob j1, const int* __restrict__ flagp){
  TJob j = (blockIdx.z==0)? j0 : j1;
  int f = flagp[0];
  if ((int)(blockIdx.x*256) >= j.D) return;
  int m0 = blockIdx.y*64;
  if (m0 >= j.M) return;
  __shared__ float xs[NB*64];
  int d = blockIdx.x*256 + threadIdx.x;
  for(int i=threadIdx.x;i<NB*64;i+=256){ int b=i>>6, mm=i&63; xs[i]=j.x[(long)b*j.M+m0+mm]; }
  __syncthreads();
  float acc[NB];
  #pragma unroll
  for(int b=0;b<NB;b++) acc[b]=0.f;
  for(int mm=0;mm<64;++mm){
    float w = getel(j.W, (long)(m0+mm)*j.D + d, f);
    #pragma unroll
    for(int b=0;b<NB;b++) acc[b] += w*xs[b*64+mm];
  }
  #pragma unroll
  for(int b=0;b<NB;b++) atomicAdd(&j.out[(long)b*j.D+d], acc[b]);
}

// ---- att1 logits -> unnormalized exp + Z1; also e20 (att2 cls-key exp).
// grid (258, NB): x<256 -> 4 keys/block; x==256 -> att1 key0; x==257 -> att2 l20.
__global__ __launch_bounds__(256) void att1_logits_z_kernel(const void* __restrict__ x1,
    const float* __restrict__ csp, const float* __restrict__ cmp,
    const float* __restrict__ q1p, const float* __restrict__ q2p,
    float* __restrict__ att1_e, float* __restrict__ Z1, float* __restrict__ e20,
    const int* __restrict__ flagp){
  __shared__ float red[4];
  int f = flagp[0];
  int b = blockIdx.y;
  int tid = threadIdx.x;
  if (blockIdx.x == 256){
    float p=0.f;
    for(int d=tid;d<DM;d+=256) p += q1p[(long)b*DM+d]*csp[(long)b*DM+d];
    float l0 = block_sum(p, red) * (1.f/22.f);
    if (tid==0){
      float e = __expf(clamp60(l0));
      att1_e[(long)b*NK1] = e;
      atomicAdd(&Z1[b], e);
    }
    return;
  }
  if (blockIdx.x == 257){
    float p=0.f;
    for(int d=tid;d<DL;d+=256) p += q2p[(long)b*DL+d]*cmp[(long)b*DL+d];
    float l2 = block_sum(p, red) * (1.f/32.f);
    if (tid==0) e20[b] = __expf(clamp60(l2));
    return;
  }
  int w = tid>>6, l = tid&63;
  int k = blockIdx.x*4 + w + 1;      // 1..1024
  long rbase = ((long)b*NM_ROWS + k)*DM + l*8;
  float rf[8];
  if (f){
    const float* rp = (const float*)x1 + rbase;
    float4 a0 = *(const float4*)rp;
    float4 a1 = *(const float4*)(rp+4);
    rf[0]=a0.x; rf[1]=a0.y; rf[2]=a0.z; rf[3]=a0.w;
    rf[4]=a1.x; rf[5]=a1.y; rf[6]=a1.z; rf[7]=a1.w;
  } else {
    uint4 rv = *(const uint4*)((const u16*)x1 + rbase);
    unpack8(rv, rf);
  }
  const float* qp = q1p + (long)b*DM + l*8;
  float s = rf[0]*qp[0]+rf[1]*qp[1]+rf[2]*qp[2]+rf[3]*qp[3]
          + rf[4]*qp[4]+rf[5]*qp[5]+rf[6]*qp[6]+rf[7]*qp[7];
  s = wsum(s);
  if (l==0){
    float e = __expf(clamp60(s*(1.f/22.f)));
    att1_e[(long)b*NK1 + k] = e;
    red[w] = e;
  }
  __syncthreads();
  if (tid==0) atomicAdd(&Z1[b], red[0]+red[1]+red[2]+red[3]);
}

// ---- att1 projection (normalization inline):
// att1w[b,m] = 0.3*((sum_k e[b,k]*proj_w[m,k])/Z1[b] + proj_b[m]) ----
__global__ __launch_bounds__(256) void att1_proj_kernel(const void* __restrict__ proj_w,
    const void* __restrict__ proj_b, const float* __restrict__ att1_e,
    const float* __restrict__ Z1, float* __restrict__ att1w,
    const int* __restrict__ flagp){
  int f = flagp[0];
  __shared__ float sm[8*1024];   // 32KB: 8 batches at a time
  __shared__ float sZ[NB];
  int tid=threadIdx.x;
  if (tid<NB) sZ[tid] = 1.f/fmaxf(Z1[tid],1e-30f);
  __syncthreads();
  int m = blockIdx.x*4 + (tid>>6);
  int l = tid&63;
  float acc[NB];
  #pragma unroll
  for(int b=0;b<NB;b++) acc[b]=0.f;
  for(int h=0;h<2;h++){
    for(int i=tid;i<8*1024;i+=256){ int bb=i>>10, k=i&1023; sm[i]=att1_e[(long)(h*8+bb)*NK1+k]; }
    __syncthreads();
    if (m < MPROJ){
      for(int k=l;k<1024;k+=64){
        float w = getel(proj_w, (long)m*NK1+k, f);
        #pragma unroll
        for(int bb=0;bb<8;bb++) acc[h*8+bb] += w * sm[bb*1024+k];
      }
    }
    __syncthreads();
  }
  if (m >= MPROJ) return;
  if(l==0){
    float wt = getel(proj_w, (long)m*NK1 + 1024, f);
    #pragma unroll
    for(int b=0;b<NB;b++) acc[b] += wt * att1_e[(long)b*NK1 + 1024];
  }
  #pragma unroll
  for(int b=0;b<NB;b++) acc[b]=wsum(acc[b]);
  if(l==0){
    float pb = getel(proj_b, m, f);
    #pragma unroll
    for(int b=0;b<NB;b++) att1w[(long)b*NK2+m] = 0.3f*(acc[b]*sZ[b]+pb);
  }
}

// ---- main pass: one read of x0. Per key k>=1:
//   l2 = clamp(q2p.row/32); e=exp(l2); s1 += att1w[k]*row; s2 += e*row; Z += e
__global__ __launch_bounds__(256) void att2_pass_kernel(const void* __restrict__ x0,
    const float* __restrict__ q2p, const float* __restrict__ att1w,
    float* __restrict__ s1, float* __restrict__ s2, float* __restrict__ Zacc,
    const int* __restrict__ flagp){
  __shared__ float ls[4][1024];
  __shared__ float zs[4];
  int f = flagp[0];
  int b = blockIdx.y;
  int w = threadIdx.x>>6, l = threadIdx.x&63;
  float qf[16];
  {
    const float* qp = q2p + (long)b*DL;
    #pragma unroll
    for(int j=0;j<8;j++){ qf[j]=qp[l*8+j]; qf[8+j]=qp[512+l*8+j]; }
  }
  float af1[16], af2[16];
  #pragma unroll
  for(int j=0;j<16;j++){ af1[j]=0.f; af2[j]=0.f; }
  float zacc=0.f;
  int kbase = blockIdx.x*64 + w*16;
  int nk = NL - kbase; if (nk > 16) nk = 16; if (nk < 0) nk = 0;
  const float* awp = att1w + (long)b*NK2 + kbase + 1;
  for(int i=0;i<nk;i++){
    float rf[16];
    long rowoff = ((long)b*NL + kbase + i)*DL;
    if (f){
      const float* rp = ((const float*)x0) + rowoff;
      float4 a0 = *(const float4*)(rp + l*8);
      float4 a1 = *(const float4*)(rp + l*8 + 4);
      float4 a2 = *(const float4*)(rp + 512 + l*8);
      float4 a3 = *(const float4*)(rp + 512 + l*8 + 4);
      rf[0]=a0.x; rf[1]=a0.y; rf[2]=a0.z; rf[3]=a0.w;
      rf[4]=a1.x; rf[5]=a1.y; rf[6]=a1.z; rf[7]=a1.w;
      rf[8]=a2.x; rf[9]=a2.y; rf[10]=a2.z; rf[11]=a2.w;
      rf[12]=a3.x; rf[13]=a3.y; rf[14]=a3.z; rf[15]=a3.w;
    } else {
      const u16* rp = ((const u16*)x0) + rowoff;
      uint4 rv0 = *(const uint4*)(rp + l*8);
      uint4 rv1 = *(const uint4*)(rp + 512 + l*8);
      u32 wd[8]={rv0.x,rv0.y,rv0.z,rv0.w,rv1.x,rv1.y,rv1.z,rv1.w};
      #pragma unroll
      for(int q=0;q<8;q++){
        union{u32 u; float x;} ua,ub;
        ua.u = wd[q]<<16; ub.u = wd[q]&0xffff0000u;
        rf[2*q]=ua.x; rf[2*q+1]=ub.x;
      }
    }
    float dp=0.f;
    #pragma unroll
    for(int j=0;j<16;j++) dp += rf[j]*qf[j];
    dp = clamp60(wsum(dp)*(1.f/32.f));
    float e = __expf(dp);
    float aw = awp[i];
    zacc += e;
    #pragma unroll
    for(int j=0;j<16;j++){ af1[j] += aw*rf[j]; af2[j] += e*rf[j]; }
  }
  #pragma unroll
  for(int c=0;c<2;c++)
    #pragma unroll
    for(int j=0;j<8;j++) ls[w][c*512 + l*8 + j] = af1[c*8+j];
  __syncthreads();
  for(int d=threadIdx.x; d<1024; d+=256)
    atomicAdd(&s1[(long)b*DL+d], ls[0][d]+ls[1][d]+ls[2][d]+ls[3][d]);
  __syncthreads();
  #pragma unroll
  for(int c=0;c<2;c++)
    #pragma unroll
    for(int j=0;j<8;j++) ls[w][c*512 + l*8 + j] = af2[c*8+j];
  if(l==0) zs[w]=zacc;
  __syncthreads();
  for(int d=threadIdx.x; d<1024; d+=256)
    atomicAdd(&s2[(long)b*DL+d], ls[0][d]+ls[1][d]+ls[2][d]+ls[3][d]);
  if(threadIdx.x==0) atomicAdd(&Zacc[b], zs[0]+zs[1]+zs[2]+zs[3]);
}

// ---- fused finalize + Wv + gs_w:  g_s[b,m] = gs_b[m] + sum_d Wfuse[m,d]*u[b,d]
// where u[b,d] = s1 + a0*cm + c7*(s2 + e0*cm), a0=att1w[b,0], c7=0.7/(Zacc[b]+e0).
__global__ __launch_bounds__(256) void jvg_kernel(const float* __restrict__ Wfuse,
    const float* __restrict__ cmp, const float* __restrict__ att1w,
    const float* __restrict__ s1, const float* __restrict__ s2,
    const float* __restrict__ Zacc, const float* __restrict__ e20,
    const void* __restrict__ gs_b, float* __restrict__ g_s,
    const int* __restrict__ flagp){
  __shared__ float xs[NB*512];
  __shared__ float sA[NB], sE[NB], sC[NB];
  int f = flagp[0];
  int tid = threadIdx.x;
  if (tid < NB){
    float e0 = e20[tid];
    float Zf = fmaxf(Zacc[tid] + e0, 1e-30f);
    sA[tid] = att1w[(long)tid*NK2];
    sE[tid] = e0;
    sC[tid] = 0.7f/Zf;
  }
  __syncthreads();
  int m = blockIdx.x*4 + (tid>>6);
  int l = tid&63;
  float acc[NB];
  #pragma unroll
  for(int b=0;b<NB;b++) acc[b]=0.f;
  for (int c0=0;c0<DL;c0+=512){
    for (int i=tid;i<NB*512;i+=256){
      int b=i>>9, dd=(i&511);
      long gi = (long)b*DL + c0 + dd;
      float cm = cmp[gi];
      xs[i] = s1[gi] + sA[b]*cm + sC[b]*(s2[gi] + sE[b]*cm);
    }
    __syncthreads();
    const float* wr = Wfuse + (long)m*DL + c0;
    for (int dd=l; dd<512; dd+=64){
      float wv = wr[dd];
      #pragma unroll
      for(int b=0;b<NB;b++) acc[b] += wv*xs[b*512+dd];
    }
    __syncthreads();
  }
  #pragma unroll
  for(int b=0;b<NB;b++) acc[b]=wsum(acc[b]);
  if (l==0){
    float bv = getel(gs_b, m, f);
    #pragma unroll
    for(int b=0;b<NB;b++) g_s[(long)b*DS+m]=acc[b]+bv;
  }
}

// ---- broadcast g_s[b] to all 4097 output rows, dtype per flag ----
__global__ __launch_bounds__(256) void broadcast_out_kernel(const float* __restrict__ g_s,
    void* __restrict__ out, const int* __restrict__ flagp){
  int f = flagp[0];
  int b = blockIdx.y;
  int colq = threadIdx.x & 31;
  int rowo = threadIdx.x >> 5;
  int r = blockIdx.x*8 + rowo;
  const float* gp = g_s + (long)b*DS + colq*8;
  float4 ga = *(const float4*)gp;
  float4 gb = *(const float4*)(gp+4);
  if (r >= NL) return;
  long row = (long)b*NL + r;
  if (f){
    float4* op = (float4*)out + row*64 + colq*2;
    op[0]=ga; op[1]=gb;
  } else {
    uint4 pk;
    pk.x = (u32)f2bf(ga.x) | ((u32)f2bf(ga.y)<<16);
    pk.y = (u32)f2bf(ga.z) | ((u32)f2bf(ga.w)<<16);
    pk.z = (u32)f2bf(gb.x) | ((u32)f2bf(gb.y)<<16);
    pk.w = (u32)f2bf(gb.z) | ((u32)f2bf(gb.w)<<16);
    ((uint4*)out)[row*32 + colq] = pk;
  }
}

extern "C" void kernel_launch(void* const* d_in, const int* in_sizes, int n_in,
                              void* d_out, int out_size, void* d_ws, size_t ws_size,
                              hipStream_t stream) {
  const void* x0     = d_in[0];
  const void* x1     = d_in[1];
  const void* x2     = d_in[2];
  const void* f_s_w  = d_in[3];
  const void* f_s_b  = d_in[4];
  const void* f_m_w  = d_in[5];
  const void* f_m_b  = d_in[6];
  const void* Wq1    = d_in[7];
  const void* Wk1    = d_in[8];
  const void* Wq2    = d_in[9];
  const void* Wk2    = d_in[10];
  const void* Wv     = d_in[11];
  const void* proj_w = d_in[12];
  const void* proj_b = d_in[13];
  const void* gs_w   = d_in[14];
  const void* gs_b   = d_in[15];

  float* ws = (float*)d_ws;
  float* csp   = ws + OFF_CSP;
  float* cmp   = ws + OFF_CMP;
  float* q1v   = ws + OFF_Q1V;
  float* q2v   = ws + OFF_Q2V;
  float* e1    = ws + OFF_E1;
  float* a1w   = ws + OFF_A1W;
  float* g_s   = ws + OFF_GS;
  float* wf    = ws + OFF_WF;
  float* q1p   = ws + OFF_Q1P;
  float* q2p   = ws + OFF_Q2P;
  float* s1    = ws + OFF_S1;
  float* s2    = ws + OFF_S2;
  float* za    = ws + OFF_ZA;
  float* z1    = ws + OFF_Z1;
  float* e20   = ws + OFF_E20;
  int*   flag  = (int*)(ws + OFF_FLAG);

  // 1. init: Wfuse (blocks 0..63) + zero accumulators (64..95) + detect (96)
  init_kernel<<<97,256,0,stream>>>(x0, gs_w, Wv, ws, flag);

  // 2. cls projections
  Job ja0{f_s_w, x2, f_s_b, csp, DM, DS, (long)NL*DS, 0};
  Job ja1{f_m_w, x1, f_m_b, cmp, DL, DM, (long)NM_ROWS*DM, 0};
  gemv_n_kernel<<<dim3(256,2),256,0,stream>>>(ja0, ja1, flag);

  // 3. q1 = Wq1@csp, q2 = Wq2@cmp
  Job jb0{Wq1, csp, nullptr, q1v, DM, DM, DM, 1};
  Job jb1{Wq2, cmp, nullptr, q2v, DL, DL, DL, 1};
  gemv_n_kernel<<<dim3(256,2),256,0,stream>>>(jb0, jb1, flag);

  // 4. q1p = Wk1^T@q1, q2p = Wk2^T@q2
  TJob jt0{Wk1, q1v, q1p, DM, DM};
  TJob jt1{Wk2, q2v, q2p, DL, DL};
  gemv_t_kernel<<<dim3(4,16,2),256,0,stream>>>(jt0, jt1, flag);

  // 5. att1 exp(logits) + Z1 + e20 (no max-sub: logits are tiny, clamped)
  att1_logits_z_kernel<<<dim3(258,NB),256,0,stream>>>(x1, csp, cmp, q1p, q2p,
      e1, z1, e20, flag);

  // 6. att1 projection (normalized, 0.3-scaled)
  att1_proj_kernel<<<dim3(1025),256,0,stream>>>(proj_w, proj_b, e1, z1, a1w, flag);

  // 7. main pass over x0
  att2_pass_kernel<<<dim3(65,NB),256,0,stream>>>(x0, q2p, a1w, s1, s2, za, flag);

  // 8. fused finalize + Wv + gs_w -> g_s
  jvg_kernel<<<dim3(64),256,0,stream>>>(wf, cmp, a1w, s1, s2, za, e20, gs_b, g_s, flag);

  // 9. broadcast
  broadcast_out_kernel<<<dim3(513,NB),256,0,stream>>>(g_s, d_out, flag);
}

// Round 3
// 815.375 us; speedup vs baseline: 1.8693x; 1.1776x over previous
//
#include <hip/hip_runtime.h>
#include <stdint.h>

typedef unsigned int u32;
typedef unsigned short u16;

#define NB 16
#define NL 4097      // x0 rows per batch (= att2 keys - 1)
#define NM_ROWS 1025 // x1 rows per batch
#define DS 256
#define DM 512
#define DL 1024
#define NK1 1025     // att1 keys
#define NK2 4098     // att2 keys
#define MPROJ 4098   // proj_w output dim

// ---- workspace layout (float offsets) ----
#define OFF_CSP  0            // 16*512
#define OFF_CMP  8192         // 16*1024
#define OFF_E1   24576        // 16*1025 unnormalized exp(att1 logits)
#define OFF_GS   40976        // 16*256
#define OFF_WF   45072        // 256*1024  Wfuse = gs_w @ Wv
#define OFF_M1T  307216       // 512*512   M1T[d,e] = sum_m Wk1[m,d]*Wq1[m,e]
#define OFF_M2T  569360       // 1024*1024 M2T[d,e] = sum_m Wk2[m,d]*Wq2[m,e]
#define OFF_Q1P  1617936      // 16*512
#define OFF_Q2P  1626128      // 16*1024
#define OFF_S1   1642512      // 16*1024 <- zeroed
#define OFF_S2   1658896      // 16*1024 <- zeroed
#define OFF_ZA   1675280      // 16      <- zeroed (att2 Z)
#define OFF_Z1   1675296      // 16      <- zeroed (att1 Z)
#define OFF_E20  1675312      // 16      <- zeroed (att2 cls-key exp)
#define OFF_FLAG 1675328      // 1 int (written every launch)
#define ZERO_U4  8204         // (OFF_FLAG-OFF_S1)/4 uint4s

__device__ __forceinline__ float bf2f(u16 h){ union{u32 u; float f;} c; c.u = ((u32)h)<<16; return c.f; }
__device__ __forceinline__ u16 f2bf(float x){ union{float f; u32 u;} c; c.f=x; u32 u=c.u; return (u16)((u + 0x7fffu + ((u>>16)&1u))>>16); }
__device__ __forceinline__ float getel(const void* p, long i, int f){
  return f ? ((const float*)p)[i] : bf2f(((const u16*)p)[i]);
}
__device__ __forceinline__ void unpack8(uint4 v, float* fo){
  u32 wd[4]={v.x,v.y,v.z,v.w};
  #pragma unroll
  for(int i=0;i<4;i++){
    union{u32 u; float x;} a,b;
    a.u = wd[i]<<16; b.u = wd[i]&0xffff0000u;
    fo[2*i]=a.x; fo[2*i+1]=b.x;
  }
}
__device__ __forceinline__ float wsum(float v){
  #pragma unroll
  for(int o=32;o>0;o>>=1) v += __shfl_xor(v,o,64);
  return v;
}
__device__ __forceinline__ float block_sum(float v, volatile float* red){
  v = wsum(v);
  if((threadIdx.x&63)==0) red[threadIdx.x>>6]=v;
  __syncthreads();
  float r = red[0]+red[1]+red[2]+red[3];
  __syncthreads();
  return r;
}
__device__ __forceinline__ float clamp60(float x){ return fminf(fmaxf(x,-60.f),60.f); }

__device__ __forceinline__ int self_detect(const void* x0, float* sh){
  // bf16 N(0,1) data -> max|bf16| ~5; fp32 bits read as u16 halves decode huge.
  float mx=0.f;
  const u16* p = (const u16*)x0;
  for (int i=threadIdx.x;i<4096;i+=256){ float v=fabsf(bf2f(p[i])); if(v==v) mx=fmaxf(mx,v); }
  sh[threadIdx.x]=mx; __syncthreads();
  if (threadIdx.x==0){
    float m=0.f;
    for (int i=0;i<256;i++) m=fmaxf(m,sh[i]);
    sh[0] = (m>1e3f)?1.f:0.f;
  }
  __syncthreads();
  int f = (sh[0]!=0.f)?1:0;
  __syncthreads();
  return f;
}

// ---- generic 4-row weight-product tile: out[r0+r, d] = sum_m A(r,m)*B[m,d]
// A element (r,m) at A[r*rstrA + m*mstrA]. B row-major, row length D.
// Thread owns 8 consecutive d; sum split across og groups; LDS reduce.
__device__ __forceinline__ void mm4(const void* A, const void* B, float* out,
    long rstrA, long mstrA, int lgS, int D, int r0, int f, float* sh){
  const int tid = threadIdx.x;
  const int SUM = 1<<lgS;
  if (mstrA == 1){
    for (int i=tid;i<4*SUM;i+=256){
      int r=i>>lgS, m=i&(SUM-1);
      sh[i] = getel(A, (long)(r0+r)*rstrA + m, f);
    }
  } else {
    for (int i=tid;i<4*SUM;i+=256){
      int r=i&3, m=i>>2;
      sh[(r<<lgS)|m] = getel(A, (long)(r0+r) + (long)m*mstrA, f);
    }
  }
  __syncthreads();
  const int nd  = D>>3;          // d-groups (64 or 128)
  const int dq  = tid & (nd-1);
  const int og  = tid / nd;      // sum-split group
  const int ogc = 256/nd;
  const int mch = SUM/ogc;
  const int d0  = dq*8;
  float acc[4][8];
  #pragma unroll
  for(int r=0;r<4;r++)
    #pragma unroll
    for(int j=0;j<8;j++) acc[r][j]=0.f;
  const int mlo = og*mch, mhi = mlo+mch;
  if (f){
    const float* Bp = (const float*)B;
    #pragma unroll 4
    for (int m=mlo;m<mhi;m++){
      float4 b0 = *(const float4*)(Bp + (long)m*D + d0);
      float4 b1 = *(const float4*)(Bp + (long)m*D + d0 + 4);
      float bv[8]={b0.x,b0.y,b0.z,b0.w,b1.x,b1.y,b1.z,b1.w};
      #pragma unroll
      for(int r=0;r<4;r++){
        float g = sh[(r<<lgS)|m];
        #pragma unroll
        for(int j=0;j<8;j++) acc[r][j] += g*bv[j];
      }
    }
  } else {
    const u16* Bp = (const u16*)B;
    #pragma unroll 4
    for (int m=mlo;m<mhi;m++){
      uint4 v = *(const uint4*)(Bp + (long)m*D + d0);
      float bv[8]; unpack8(v,bv);
      #pragma unroll
      for(int r=0;r<4;r++){
        float g = sh[(r<<lgS)|m];
        #pragma unroll
        for(int j=0;j<8;j++) acc[r][j] += g*bv[j];
      }
    }
  }
  __syncthreads();
  for (int p=1;p<ogc;p++){
    if (og==p){
      #pragma unroll
      for(int r=0;r<4;r++)
        #pragma unroll
        for(int j=0;j<8;j++) sh[dq*32 + r*8 + j] = acc[r][j];
    }
    __syncthreads();
    if (og==0){
      #pragma unroll
      for(int r=0;r<4;r++)
        #pragma unroll
        for(int j=0;j<8;j++) acc[r][j] += sh[dq*32 + r*8 + j];
    }
    __syncthreads();
  }
  if (og==0){
    #pragma unroll
    for(int r=0;r<4;r++){
      float4 o0={acc[r][0],acc[r][1],acc[r][2],acc[r][3]};
      float4 o1={acc[r][4],acc[r][5],acc[r][6],acc[r][7]};
      *(float4*)(out + (long)(r0+r)*D + d0) = o0;
      *(float4*)(out + (long)(r0+r)*D + d0 + 4) = o1;
    }
  }
}

// ---- init: Wfuse (blk 0..63), M1T (64..191), M2T (192..447), zero (448..479),
//      detect (480) ----
__global__ __launch_bounds__(256) void init_kernel(const void* __restrict__ x0,
    const void* __restrict__ gs_w, const void* __restrict__ Wv,
    const void* __restrict__ Wq1, const void* __restrict__ Wk1,
    const void* __restrict__ Wq2, const void* __restrict__ Wk2,
    float* __restrict__ ws, int* __restrict__ flag){
  __shared__ float sh[4096];
  int blk = blockIdx.x, tid = threadIdx.x;
  if (blk >= 448 && blk < 480){
    uint4 z; z.x=0u; z.y=0u; z.z=0u; z.w=0u;
    uint4* zp = (uint4*)(ws + OFF_S1);
    for (int i=(blk-448)*256+tid; i<ZERO_U4; i+=32*256) zp[i]=z;
    return;
  }
  if (blk == 480){
    int f = self_detect(x0, sh);
    if (tid==0) flag[0]=f;
    return;
  }
  int f = self_detect(x0, sh);
  if (blk < 64){
    mm4(gs_w, Wv, ws+OFF_WF, DL, 1, 10, DL, blk*4, f, sh);          // Wfuse
  } else if (blk < 192){
    mm4(Wk1, Wq1, ws+OFF_M1T, 1, DM, 9, DM, (blk-64)*4, f, sh);     // M1T
  } else {
    mm4(Wk2, Wq2, ws+OFF_M2T, 1, DL, 10, DL, (blk-192)*4, f, sh);   // M2T
  }
}

// ---- batched matvec: out[b,m] = bias[m] + sum_d W[m,d]*x[b,d] ----
struct Job {
  const void* W; const void* x; const void* bias; float* out;
  int M, D; long xstride; int xinws; int winws;
};

__global__ __launch_bounds__(256) void gemv_n_kernel(Job j0, Job j1, const int* __restrict__ flagp){
  Job j = (blockIdx.y==0)? j0 : j1;
  if ((int)(blockIdx.x*4) >= j.M) return;
  int f = flagp[0];
  __shared__ float xs[NB*512];
  int tid = threadIdx.x;
  int m = blockIdx.x*4 + (tid>>6);
  int l = tid & 63;
  float acc[NB];
  #pragma unroll
  for(int b=0;b<NB;b++) acc[b]=0.f;
  for(int c0=0;c0<j.D;c0+=512){
    int cl = j.D-c0; if (cl>512) cl=512;
    for(int i=tid;i<NB*cl;i+=256){
      int b=i/cl, d=i-b*cl;
      float v;
      if (j.xinws) v = ((const float*)j.x)[(long)b*j.D + c0 + d];
      else         v = getel(j.x, (long)b*j.xstride + c0 + d, f);
      xs[i]=v;
    }
    __syncthreads();
    if (m < j.M){
      for(int d=l; d<cl; d+=64){
        float w = j.winws ? ((const float*)j.W)[(long)m*j.D + c0 + d]
                          : getel(j.W, (long)m*j.D + c0 + d, f);
        #pragma unroll
        for(int b=0;b<NB;b++) acc[b] += w*xs[b*cl+d];
      }
    }
    __syncthreads();
  }
  if (m >= j.M) return;
  #pragma unroll
  for(int b=0;b<NB;b++) acc[b]=wsum(acc[b]);
  if(l==0){
    float bv = j.bias ? getel(j.bias, m, f) : 0.f;
    #pragma unroll
    for(int b=0;b<NB;b++) j.out[(long)b*j.M+m]=acc[b]+bv;
  }
}

// ---- att1 exp(logits)+Z1 for keys 1..1024; key0; e20.
// grid (258, NB): x<256 -> 4 keys/block; x==256 -> att1 key0; x==257 -> att2 l20.
__global__ __launch_bounds__(256) void att1_logits_z_kernel(const void* __restrict__ x1,
    const float* __restrict__ csp, const float* __restrict__ cmp,
    const float* __restrict__ q1p, const float* __restrict__ q2p,
    float* __restrict__ att1_e, float* __restrict__ Z1, float* __restrict__ e20,
    const int* __restrict__ flagp){
  __shared__ float red[4];
  int f = flagp[0];
  int b = blockIdx.y;
  int tid = threadIdx.x;
  if (blockIdx.x == 256){
    float p=0.f;
    for(int d=tid;d<DM;d+=256) p += q1p[(long)b*DM+d]*csp[(long)b*DM+d];
    float l0 = block_sum(p, red) * (1.f/22.f);
    if (tid==0){
      float e = __expf(clamp60(l0));
      att1_e[(long)b*NK1] = e;
      atomicAdd(&Z1[b], e);
    }
    return;
  }
  if (blockIdx.x == 257){
    float p=0.f;
    for(int d=tid;d<DL;d+=256) p += q2p[(long)b*DL+d]*cmp[(long)b*DL+d];
    float l2 = block_sum(p, red) * (1.f/32.f);
    if (tid==0) e20[b] = __expf(clamp60(l2));
    return;
  }
  int w = tid>>6, l = tid&63;
  int k = blockIdx.x*4 + w + 1;      // 1..1024
  long rbase = ((long)b*NM_ROWS + k)*DM + l*8;
  float rf[8];
  if (f){
    const float* rp = (const float*)x1 + rbase;
    float4 a0 = *(const float4*)rp;
    float4 a1 = *(const float4*)(rp+4);
    rf[0]=a0.x; rf[1]=a0.y; rf[2]=a0.z; rf[3]=a0.w;
    rf[4]=a1.x; rf[5]=a1.y; rf[6]=a1.z; rf[7]=a1.w;
  } else {
    uint4 rv = *(const uint4*)((const u16*)x1 + rbase);
    unpack8(rv, rf);
  }
  const float* qp = q1p + (long)b*DM + l*8;
  float s = rf[0]*qp[0]+rf[1]*qp[1]+rf[2]*qp[2]+rf[3]*qp[3]
          + rf[4]*qp[4]+rf[5]*qp[5]+rf[6]*qp[6]+rf[7]*qp[7];
  s = wsum(s);
  if (l==0){
    float e = __expf(clamp60(s*(1.f/22.f)));
    att1_e[(long)b*NK1 + k] = e;
    red[w] = e;
  }
  __syncthreads();
  if (tid==0) atomicAdd(&Z1[b], red[0]+red[1]+red[2]+red[3]);
}

// ---- main pass over x0 with fused att1-weight computation.
// Per key k>=1 (m = k): aw = dot(e1*0.3/Z1, proj_w[m,:]) + 0.3*proj_b[m];
// l2 = clamp(q2p.row/32); e=exp(l2); s1 += aw*row; s2 += e*row; Z += e.
__global__ __launch_bounds__(256) void att2_pass_kernel(const void* __restrict__ x0,
    const float* __restrict__ q2p, const float* __restrict__ att1_e,
    const float* __restrict__ Z1, const void* __restrict__ proj_w,
    const void* __restrict__ proj_b,
    float* __restrict__ s1, float* __restrict__ s2, float* __restrict__ Zacc,
    const int* __restrict__ flagp){
  __shared__ float ls[4][1024];
  __shared__ float zs[4];
  __shared__ float es[NK1];
  int f = flagp[0];
  int b = blockIdx.y;
  int w = threadIdx.x>>6, l = threadIdx.x&63;
  {
    float zi = 0.3f/fmaxf(Z1[b],1e-30f);
    for (int i=threadIdx.x;i<NK1;i+=256) es[i] = att1_e[(long)b*NK1+i]*zi;
  }
  float qf[16];
  {
    const float* qp = q2p + (long)b*DL;
    #pragma unroll
    for(int j=0;j<8;j++){ qf[j]=qp[l*8+j]; qf[8+j]=qp[512+l*8+j]; }
  }
  __syncthreads();
  float af1[16], af2[16];
  #pragma unroll
  for(int j=0;j<16;j++){ af1[j]=0.f; af2[j]=0.f; }
  float zacc=0.f;
  int kbase = blockIdx.x*64 + w*16;
  int nk = NL - kbase; if (nk > 16) nk = 16; if (nk < 0) nk = 0;
  for(int i=0;i<nk;i++){
    int m = kbase + i + 1;
    // fused att1 weight
    float a=0.f;
    for(int j2=l;j2<NK1;j2+=64) a += es[j2]*getel(proj_w,(long)m*NK1+j2,f);
    a = wsum(a) + 0.3f*getel(proj_b, m, f);
    float rf[16];
    long rowoff = ((long)b*NL + kbase + i)*DL;
    if (f){
      const float* rp = ((const float*)x0) + rowoff;
      float4 a0 = *(const float4*)(rp + l*8);
      float4 a1 = *(const float4*)(rp + l*8 + 4);
      float4 a2 = *(const float4*)(rp + 512 + l*8);
      float4 a3 = *(const float4*)(rp + 512 + l*8 + 4);
      rf[0]=a0.x; rf[1]=a0.y; rf[2]=a0.z; rf[3]=a0.w;
      rf[4]=a1.x; rf[5]=a1.y; rf[6]=a1.z; rf[7]=a1.w;
      rf[8]=a2.x; rf[9]=a2.y; rf[10]=a2.z; rf[11]=a2.w;
      rf[12]=a3.x; rf[13]=a3.y; rf[14]=a3.z; rf[15]=a3.w;
    } else {
      const u16* rp = ((const u16*)x0) + rowoff;
      uint4 rv0 = *(const uint4*)(rp + l*8);
      uint4 rv1 = *(const uint4*)(rp + 512 + l*8);
      u32 wd[8]={rv0.x,rv0.y,rv0.z,rv0.w,rv1.x,rv1.y,rv1.z,rv1.w};
      #pragma unroll
      for(int q=0;q<8;q++){
        union{u32 u; float x;} ua,ub;
        ua.u = wd[q]<<16; ub.u = wd[q]&0xffff0000u;
        rf[2*q]=ua.x; rf[2*q+1]=ub.x;
      }
    }
    float dp=0.f;
    #pragma unroll
    for(int j=0;j<16;j++) dp += rf[j]*qf[j];
    dp = clamp60(wsum(dp)*(1.f/32.f));
    float e = __expf(dp);
    zacc += e;
    #pragma unroll
    for(int j=0;j<16;j++){ af1[j] += a*rf[j]; af2[j] += e*rf[j]; }
  }
  #pragma unroll
  for(int c=0;c<2;c++)
    #pragma unroll
    for(int j=0;j<8;j++) ls[w][c*512 + l*8 + j] = af1[c*8+j];
  __syncthreads();
  for(int d=threadIdx.x; d<1024; d+=256)
    atomicAdd(&s1[(long)b*DL+d], ls[0][d]+ls[1][d]+ls[2][d]+ls[3][d]);
  __syncthreads();
  #pragma unroll
  for(int c=0;c<2;c++)
    #pragma unroll
    for(int j=0;j<8;j++) ls[w][c*512 + l*8 + j] = af2[c*8+j];
  if(l==0) zs[w]=zacc;
  __syncthreads();
  for(int d=threadIdx.x; d<1024; d+=256)
    atomicAdd(&s2[(long)b*DL+d], ls[0][d]+ls[1][d]+ls[2][d]+ls[3][d]);
  if(threadIdx.x==0) atomicAdd(&Zacc[b], zs[0]+zs[1]+zs[2]+zs[3]);
}

// ---- fused finalize + Wv + gs_w: g_s[b,m] = gs_b[m] + sum_d Wfuse[m,d]*u[b,d]
// u[b,d] = s1 + a0*cm + c7*(s2 + e0*cm); a0 = 0.3*(dot(e1,pw0)/Z1 + pb0).
__global__ __launch_bounds__(256) void jvg_kernel(const float* __restrict__ Wfuse,
    const float* __restrict__ cmp, const float* __restrict__ att1_e,
    const float* __restrict__ Z1, const void* __restrict__ proj_w,
    const void* __restrict__ proj_b,
    const float* __restrict__ s1, const float* __restrict__ s2,
    const float* __restrict__ Zacc, const float* __restrict__ e20,
    const void* __restrict__ gs_b, float* __restrict__ g_s,
    const int* __restrict__ flagp){
  __shared__ float xs[NB*512];
  __shared__ float pw0[NK1];
  __shared__ float sA[NB], sE[NB], sC[NB];
  int f = flagp[0];
  int tid = threadIdx.x;
  for (int i=tid;i<NK1;i+=256) pw0[i]=getel(proj_w, i, f);
  __syncthreads();
  {
    int bb = tid>>4, ll = tid&15;
    float a=0.f;
    for (int j=ll;j<NK1;j+=16) a += att1_e[(long)bb*NK1+j]*pw0[j];
    #pragma unroll
    for (int o=8;o>0;o>>=1) a += __shfl_xor(a,o,64);
    if (ll==0) sA[bb]=a;
  }
  __syncthreads();
  if (tid < NB){
    float pb0 = getel(proj_b, 0, f);
    float a0 = 0.3f*(sA[tid]/fmaxf(Z1[tid],1e-30f) + pb0);
    float e0 = e20[tid];
    float Zf = fmaxf(Zacc[tid] + e0, 1e-30f);
    sA[tid] = a0;
    sE[tid] = e0;
    sC[tid] = 0.7f/Zf;
  }
  __syncthreads();
  int m = blockIdx.x*4 + (tid>>6);
  int l = tid&63;
  float acc[NB];
  #pragma unroll
  for(int b=0;b<NB;b++) acc[b]=0.f;
  for (int c0=0;c0<DL;c0+=512){
    for (int i=tid;i<NB*512;i+=256){
      int b=i>>9, dd=(i&511);
      long gi = (long)b*DL + c0 + dd;
      float cm = cmp[gi];
      xs[i] = s1[gi] + sA[b]*cm + sC[b]*(s2[gi] + sE[b]*cm);
    }
    __syncthreads();
    const float* wr = Wfuse + (long)m*DL + c0;
    for (int dd=l; dd<512; dd+=64){
      float wv = wr[dd];
      #pragma unroll
      for(int b=0;b<NB;b++) acc[b] += wv*xs[b*512+dd];
    }
    __syncthreads();
  }
  #pragma unroll
  for(int b=0;b<NB;b++) acc[b]=wsum(acc[b]);
  if (l==0){
    float bv = getel(gs_b, m, f);
    #pragma unroll
    for(int b=0;b<NB;b++) g_s[(long)b*DS+m]=acc[b]+bv;
  }
}

// ---- broadcast g_s[b] to all 4097 output rows, dtype per flag ----
__global__ __launch_bounds__(256) void broadcast_out_kernel(const float* __restrict__ g_s,
    void* __restrict__ out, const int* __restrict__ flagp){
  int f = flagp[0];
  int b = blockIdx.y;
  int colq = threadIdx.x & 31;
  int rowo = threadIdx.x >> 5;
  int r = blockIdx.x*8 + rowo;
  const float* gp = g_s + (long)b*DS + colq*8;
  float4 ga = *(const float4*)gp;
  float4 gb = *(const float4*)(gp+4);
  if (r >= NL) return;
  long row = (long)b*NL + r;
  if (f){
    float4* op = (float4*)out + row*64 + colq*2;
    op[0]=ga; op[1]=gb;
  } else {
    uint4 pk;
    pk.x = (u32)f2bf(ga.x) | ((u32)f2bf(ga.y)<<16);
    pk.y = (u32)f2bf(ga.z) | ((u32)f2bf(ga.w)<<16);
    pk.z = (u32)f2bf(gb.x) | ((u32)f2bf(gb.y)<<16);
    pk.w = (u32)f2bf(gb.z) | ((u32)f2bf(gb.w)<<16);
    ((uint4*)out)[row*32 + colq] = pk;
  }
}

extern "C" void kernel_launch(void* const* d_in, const int* in_sizes, int n_in,
                              void* d_out, int out_size, void* d_ws, size_t ws_size,
                              hipStream_t stream) {
  const void* x0     = d_in[0];
  const void* x1     = d_in[1];
  const void* x2     = d_in[2];
  const void* f_s_w  = d_in[3];
  const void* f_s_b  = d_in[4];
  const void* f_m_w  = d_in[5];
  const void* f_m_b  = d_in[6];
  const void* Wq1    = d_in[7];
  const void* Wk1    = d_in[8];
  const void* Wq2    = d_in[9];
  const void* Wk2    = d_in[10];
  const void* Wv     = d_in[11];
  const void* proj_w = d_in[12];
  const void* proj_b = d_in[13];
  const void* gs_w   = d_in[14];
  const void* gs_b   = d_in[15];

  float* ws = (float*)d_ws;
  float* csp  = ws + OFF_CSP;
  float* cmp  = ws + OFF_CMP;
  float* e1   = ws + OFF_E1;
  float* g_s  = ws + OFF_GS;
  float* wf   = ws + OFF_WF;
  float* m1t  = ws + OFF_M1T;
  float* m2t  = ws + OFF_M2T;
  float* q1p  = ws + OFF_Q1P;
  float* q2p  = ws + OFF_Q2P;
  float* s1   = ws + OFF_S1;
  float* s2   = ws + OFF_S2;
  float* za   = ws + OFF_ZA;
  float* z1   = ws + OFF_Z1;
  float* e20  = ws + OFF_E20;
  int*   flag = (int*)(ws + OFF_FLAG);

  // 1. init: Wfuse + M1T + M2T + zero accumulators + detect
  init_kernel<<<481,256,0,stream>>>(x0, gs_w, Wv, Wq1, Wk1, Wq2, Wk2, ws, flag);

  // 2. cls projections
  Job ja0{f_s_w, x2, f_s_b, csp, DM, DS, (long)NL*DS, 0, 0};
  Job ja1{f_m_w, x1, f_m_b, cmp, DL, DM, (long)NM_ROWS*DM, 0, 0};
  gemv_n_kernel<<<dim3(256,2),256,0,stream>>>(ja0, ja1, flag);

  // 3. q1p = csp@M1T^T-style, q2p = cmp@M2T (direct writes, no atomics)
  Job jb0{m1t, csp, nullptr, q1p, DM, DM, DM, 1, 1};
  Job jb1{m2t, cmp, nullptr, q2p, DL, DL, DL, 1, 1};
  gemv_n_kernel<<<dim3(256,2),256,0,stream>>>(jb0, jb1, flag);

  // 4. att1 exp(logits) + Z1 + e20
  att1_logits_z_kernel<<<dim3(258,NB),256,0,stream>>>(x1, csp, cmp, q1p, q2p,
      e1, z1, e20, flag);

  // 5. main pass over x0 (att1-proj fused in)
  att2_pass_kernel<<<dim3(65,NB),256,0,stream>>>(x0, q2p, e1, z1, proj_w, proj_b,
      s1, s2, za, flag);

  // 6. fused finalize + Wv + gs_w -> g_s
  jvg_kernel<<<dim3(64),256,0,stream>>>(wf, cmp, e1, z1, proj_w, proj_b,
      s1, s2, za, e20, gs_b, g_s, flag);

  // 7. broadcast
  broadcast_out_kernel<<<dim3(513,NB),256,0,stream>>>(g_s, d_out, flag);
}